// Round 8
// baseline (162.532 us; speedup 1.0000x reference)
//
#include <hip/hip_runtime.h>
#include <hip/hip_bf16.h>

// Motion-detection Gauss-LIF SNN:
//   K01 (fused, heterogeneous 512-thread blocks):
//     blocks [0,512):    conv(16x9x9) via MFMA bf16 16x16x32 + LIF1 ->
//                        Z1 [800][65536] i8 {0,1} in k'-order. T-PAIRED:
//                        waves 0-3 conv(t), waves 4-7 conv(t+1) -> LDS scratch,
//                        waves 0-3 do LIF(t), LIF(t+1). Quad-buffered tiles.
//     blocks [512,6912): w1 -> i8 (A,B) split, k'-permuted, conflict-free LDS.
//   K2: Z1 @ w1^T via two mfma_i32_16x16x64_i8 (exact i32), k-split partials.
//   K2b: reduce partials; K3: sequential LIF2+FC2+LIF3 scan.
// LIF recurrences __fmul_rn/__fadd_rn (no contract). Deterministic order.

typedef __attribute__((ext_vector_type(8))) short short8;
typedef __attribute__((ext_vector_type(4))) float f32x4;
typedef __attribute__((ext_vector_type(4))) int   i32x4;

#define B_   16
#define T_   50
#define HW_  4096
#define K1N  65536
#define M_   800
#define N2_  200
#define NP_  256
#define KSPL 64
#define BM2  64
#define BK2  64
#define KCH  (K1N / KSPL)  // 1024
#define MT2  13
#define SW   84            // conv tile stride (ushorts)
#define TILE 1008          // 12 * SW
#define NCONV 512
#define NPERM (200 * 32)

// smem byte offsets (conv path)
#define OFF_AH   0
#define OFF_ALO  5120
#define OFF_TT   10240     // 4 bufs x 2 limbs x 2016B = 16128
#define OFF_SCR  26368     // 8192B scratch
#define SMEM_SZ  34560

static __device__ __forceinline__ short8 mk8(uint a, uint b, uint c, uint d){
  union { uint u[4]; short8 v; } x;
  x.u[0] = a; x.u[1] = b; x.u[2] = c; x.u[3] = d;
  return x.v;
}
static __device__ __forceinline__ uint fnl(uint a, uint b){ return (a >> 16) | (b << 16); }

template<bool WODD>
static __device__ __forceinline__ void rd5(const uint* p, int dw, uint e[5]){
  if (WODD){
    e[0] = p[dw];
    uint2 a = *(const uint2*)(p + dw + 1);
    uint2 b = *(const uint2*)(p + dw + 3);
    e[1] = a.x; e[2] = a.y; e[3] = b.x; e[4] = b.y;
  } else {
    uint2 a = *(const uint2*)(p + dw);
    uint2 b = *(const uint2*)(p + dw + 2);
    e[0] = a.x; e[1] = a.y; e[2] = b.x; e[3] = b.y;
    e[4] = p[dw + 4];
  }
}

template<bool WODD>
static __device__ __forceinline__ void conv_phase(const uint* T0, const uint* T1,
                                                  const ushort* alB, int bdw,
                                                  const short8 (&afh)[5],
                                                  f32x4& acc0, f32x4& acc1){
  #pragma unroll
  for (int ks = 0; ks < 5; ++ks){
    const int dw = bdw + SW * ks;
    short8 afl = *(const short8*)(alB + ks * 32);
    uint h[5], m[5];
    rd5<WODD>(T0, dw, h);
    rd5<WODD>(T1, dw, m);
    short8 bh0 = mk8(h[0], h[1], h[2], h[3]);
    short8 bm0 = mk8(m[0], m[1], m[2], m[3]);
    acc0 = __builtin_amdgcn_mfma_f32_16x16x32_bf16(afh[ks], bh0, acc0, 0, 0, 0);
    acc0 = __builtin_amdgcn_mfma_f32_16x16x32_bf16(afh[ks], bm0, acc0, 0, 0, 0);
    acc0 = __builtin_amdgcn_mfma_f32_16x16x32_bf16(afl,     bh0, acc0, 0, 0, 0);
    short8 bh1 = mk8(fnl(h[0], h[1]), fnl(h[1], h[2]), fnl(h[2], h[3]), fnl(h[3], h[4]));
    short8 bm1 = mk8(fnl(m[0], m[1]), fnl(m[1], m[2]), fnl(m[2], m[3]), fnl(m[3], m[4]));
    acc1 = __builtin_amdgcn_mfma_f32_16x16x32_bf16(afh[ks], bh1, acc1, 0, 0, 0);
    acc1 = __builtin_amdgcn_mfma_f32_16x16x32_bf16(afh[ks], bm1, acc1, 0, 0, 0);
    acc1 = __builtin_amdgcn_mfma_f32_16x16x32_bf16(afl,     bh1, acc1, 0, 0, 0);
  }
}

static __device__ __forceinline__ void stage_tile(ushort* Th, ushort* Tm,
                                                  int eb, float4 f){
  float vv[4] = {f.x, f.y, f.z, f.w};
  ushort sh[4], sm[4];
  #pragma unroll
  for (int ii = 0; ii < 4; ++ii){
    __hip_bfloat16 h = __float2bfloat16(vv[ii]);
    float t1 = vv[ii] - __bfloat162float(h);
    __hip_bfloat16 m = __float2bfloat16(t1);
    sh[ii] = *reinterpret_cast<ushort*>(&h);
    sm[ii] = *reinterpret_cast<ushort*>(&m);
  }
  *(ushort4*)(Th + eb) = make_ushort4(sh[0], sh[1], sh[2], sh[3]);
  *(ushort4*)(Tm + eb) = make_ushort4(sm[0], sm[1], sm[2], sm[3]);
}

// ---------------------------------------------------------------- K01
__global__ __launch_bounds__(512) void k01_fused(const float* __restrict__ x,
                                                 const float* __restrict__ kern,
                                                 const float* __restrict__ w1,
                                                 unsigned char* __restrict__ zout,
                                                 char* __restrict__ wa,
                                                 char* __restrict__ wb){
  __shared__ __align__(16) char smem[SMEM_SZ];
  const int bid = blockIdx.x;
  const int tid = threadIdx.x;

  if (bid >= NCONV){
    // ---------------- w1 -> i8 (A,B) split + k'-permute, conflict-free ------
    uint* la = (uint*)smem;               // 520 uints (o-padded)
    uint* lb = (uint*)(smem + 2112);
    const int bid2 = bid - NCONV;
    const int n = bid2 >> 5;
    const int strip = bid2 & 31;
    {
      const int q = tid >> 7, p128 = tid & 127;
      const float* src = w1 + (size_t)n * K1N + strip * 128 + p128 + q * 4 * 4096;
      uint ua = 0, ub = 0;
      #pragma unroll
      for (int r = 0; r < 3 + 1; ++r){
        float v = src[r * 4096];
        float af = rintf(v * 16384.f);
        float rr = v - af * 0x1p-14f;
        float bf = rintf(rr * 0x1p22f);
        int A = (int)af, Bq = (int)bf;
        if (Bq == 128){ A += 1; Bq = -128; }
        ua |= ((uint)(A & 255)) << (8 * r);
        ub |= ((uint)(Bq & 255)) << (8 * r);
      }
      const int o = p128 & 7, s = p128 >> 3;
      const int u = 64 * o + 4 * s + q + o;   // +o pad: bank = (o+4s+q)&31, <=2-way
      la[u] = ua;
      lb[u] = ub;
    }
    __syncthreads();
    {
      const int j0 = 2 * (tid & 255);
      const int o2 = j0 >> 6;
      const uint* s2 = (tid < 256) ? la : lb;
      uint v0 = s2[j0 + o2], v1 = s2[j0 + 1 + o2];
      char* dst = (tid < 256) ? wa : wb;
      *(uint2*)(dst + (size_t)n * K1N + strip * 2048 + j0 * 4) = make_uint2(v0, v1);
    }
    return;
  }

  // ---------------- conv + LIF1, t-paired ----------------
  ushort* Ah  = (ushort*)(smem + OFF_AH);
  ushort* Alo = (ushort*)(smem + OFF_ALO);
  float*  scr = (float*)(smem + OFF_SCR);
  auto tile = [&](int buf, int limb) -> ushort* {
    return (ushort*)(smem + OFF_TT) + (buf * 2 + limb) * TILE;
  };

  const int strip = bid & 31;
  const int b = bid >> 5;
  const int wv = tid >> 6;       // 0..7
  const int grp = wv >> 2;       // 0: even t, 1: odd t
  const int w = wv & 3;          // offset-pair index (offsets 2w, 2w+1)
  const int l = tid & 63;
  const int q = l >> 4;
  const int s = l & 15;

  // taps: kh + kl bf16 split, zero-padded to 10x16
  for (int slot = tid; slot < 16 * 160; slot += 512){
    int ch = slot / 160, kk = slot - ch * 160;
    int dy = kk >> 4, dx = kk & 15;
    float v = 0.f;
    if (dy < 9 && dx < 9) v = kern[ch * 81 + dy * 9 + dx];
    __hip_bfloat16 h = __float2bfloat16(v);
    float hf = __bfloat162float(h);
    __hip_bfloat16 lo = __float2bfloat16(v - hf);
    Ah[slot]  = *reinterpret_cast<ushort*>(&h);
    Alo[slot] = *reinterpret_cast<ushort*>(&lo);
  }

  // staging geometry: group0 = tid<240 (even t), group1 = 256<=tid<496 (odd t)
  const int st = tid & 255;
  const bool sact = st < 240;
  const int sr = st / 20, sc4 = st - sr * 20;
  const int r0 = 2 * strip - 4;
  const int imr = r0 + sr;
  const bool sin = sact && imr >= 0 && imr < 64 && sc4 >= 1 && sc4 <= 16;
  const float* xb = x + (size_t)b * (T_ * HW_);
  const float* xsrc = xb + (sin ? (imr * 64 + (sc4 - 1) * 4) : 0);
  const int eb = sr * SW + sc4 * 4;

  // initial staging: group0 -> t=0 -> buf0; group1 -> t=1 -> buf1
  if (sact){
    float4 f0 = make_float4(0.f, 0.f, 0.f, 0.f);
    if (sin) f0 = *(const float4*)(xsrc + (size_t)grp * HW_);
    stage_tile(tile(grp, 0), tile(grp, 1), eb, f0);
  }

  short8 afh[5];
  {
    // wait for taps (first loop barrier also covers; preload after barrier instead)
  }

  const int p0 = (s >> 3) + (q >> 1);
  const int bdw = 42 * p0 + 4 * (s & 7) + 4 * (q & 1) + w;
  const bool wodd = (w & 1) != 0;
  const ushort* alB = Alo + s * 160 + q * 8;

  float m1v[2][4];
  #pragma unroll
  for (int oi = 0; oi < 2; ++oi)
    #pragma unroll
    for (int r = 0; r < 4; ++r) m1v[oi][r] = 0.f;

  bool afdone = false;

  for (int p = 0; p < T_ / 2; ++p){
    __syncthreads();                               // A: tiles for 2p, 2p+1 ready
    if (!afdone){
      #pragma unroll
      for (int ks = 0; ks < 5; ++ks)
        afh[ks] = *(const short8*)(Ah + s * 160 + ks * 32 + q * 8);
      afdone = true;
    }
    const bool pf = (p < T_ / 2 - 1);
    float4 nfx = make_float4(0.f, 0.f, 0.f, 0.f);
    if (pf && sin) nfx = *(const float4*)(xsrc + (size_t)(2 * p + 2 + grp) * HW_);

    const int myBuf = (2 * p + grp) & 3;
    const uint* T0 = (const uint*)tile(myBuf, 0);
    const uint* T1 = (const uint*)tile(myBuf, 1);
    f32x4 acc0 = (f32x4)(0.f), acc1 = (f32x4)(0.f);
    if (wodd) conv_phase<true >(T0, T1, alB, bdw, afh, acc0, acc1);
    else      conv_phase<false>(T0, T1, alB, bdw, afh, acc0, acc1);

    if (grp == 1){
      #pragma unroll
      for (int r = 0; r < 4; ++r){
        scr[r * 256 + w * 64 + l]       = acc0[r];
        scr[(4 + r) * 256 + w * 64 + l] = acc1[r];
      }
    }
    __syncthreads();                               // B: scratch ready

    if (grp == 0){
      float g1v[8];
      #pragma unroll
      for (int r = 0; r < 8; ++r) g1v[r] = scr[r * 256 + w * 64 + l];
      const size_t zb  = ((size_t)(2 * p) * B_ + b) * K1N + strip * 2048 + s * 16 + q * 4;
      const size_t zb1 = zb + (size_t)B_ * K1N;
      // t = 2p
      {
        uint zw = 0;
        #pragma unroll
        for (int r = 0; r < 4; ++r){
          float m = m1v[0][r];
          float nm = (m > 1.0f) ? 0.0f : __fadd_rn(__fmul_rn(0.9f, m), acc0[r]);
          m1v[0][r] = nm;
          if (nm > 1.0f) zw |= (1u << (8 * r));
        }
        *(uint*)(zout + zb + (size_t)(2 * w) * 256) = zw;
      }
      {
        uint zw = 0;
        #pragma unroll
        for (int r = 0; r < 4; ++r){
          float m = m1v[1][r];
          float nm = (m > 1.0f) ? 0.0f : __fadd_rn(__fmul_rn(0.9f, m), acc1[r]);
          m1v[1][r] = nm;
          if (nm > 1.0f) zw |= (1u << (8 * r));
        }
        *(uint*)(zout + zb + (size_t)(2 * w + 1) * 256) = zw;
      }
      // t = 2p+1 (g from scratch)
      {
        uint zw = 0;
        #pragma unroll
        for (int r = 0; r < 4; ++r){
          float m = m1v[0][r];
          float nm = (m > 1.0f) ? 0.0f : __fadd_rn(__fmul_rn(0.9f, m), g1v[r]);
          m1v[0][r] = nm;
          if (nm > 1.0f) zw |= (1u << (8 * r));
        }
        *(uint*)(zout + zb1 + (size_t)(2 * w) * 256) = zw;
      }
      {
        uint zw = 0;
        #pragma unroll
        for (int r = 0; r < 4; ++r){
          float m = m1v[1][r];
          float nm = (m > 1.0f) ? 0.0f : __fadd_rn(__fmul_rn(0.9f, m), g1v[4 + r]);
          m1v[1][r] = nm;
          if (nm > 1.0f) zw |= (1u << (8 * r));
        }
        *(uint*)(zout + zb1 + (size_t)(2 * w + 1) * 256) = zw;
      }
    }

    if (pf && sact){
      const int sb = (2 * p + 2 + grp) & 3;        // group0 -> t+2, group1 -> t+3
      stage_tile(tile(sb, 0), tile(sb, 1), eb, nfx);
    }
  }
}

// ---------------------------------------------------------------- K2 prefetch loader (i8)
static __device__ __forceinline__ void k2_load(const unsigned char* __restrict__ z,
                                               const char* __restrict__ wa,
                                               const char* __restrict__ wb,
                                               int m0, int kg, int tid,
                                               uint4& pa, uint4 pb[8]){
  {
    int row = tid >> 2, c16 = tid & 3;
    int m = m0 + row;
    pa = make_uint4(0, 0, 0, 0);
    if (m < M_) pa = *(const uint4*)(z + (size_t)m * K1N + kg + c16 * 16);
  }
  #pragma unroll
  for (int i = 0; i < 8; ++i){
    int idx = tid + 256 * i;
    int sel = idx >> 10;
    int r   = (idx >> 2) & 255;
    int c16 = idx & 3;
    const char* src = sel ? wb : wa;
    pb[i] = make_uint4(0, 0, 0, 0);
    if (r < N2_) pb[i] = *(const uint4*)(src + (size_t)r * K1N + kg + c16 * 16);
  }
}

// ---------------------------------------------------------------- K2: i8 MFMA GEMM
__global__ __launch_bounds__(256, 2) void k2_gemm(const unsigned char* __restrict__ z,
                                                  const char* __restrict__ wa,
                                                  const char* __restrict__ wb,
                                                  float* __restrict__ P){
  __shared__ __align__(16) unsigned char Al[64 * 80];
  __shared__ __align__(16) unsigned char Bw[512 * 80];

  const int bid = blockIdx.x;
  const int L = (bid & 7) * 104 + (bid >> 3);
  const int ks = L / MT2;
  const int mt = L % MT2;
  const int m0 = mt * BM2;
  const int k0 = ks * KCH;
  const int tid = threadIdx.x;
  const int w  = tid >> 6;
  const int l  = tid & 63;
  const int lr = l & 15;
  const int lq = l >> 4;

  const i32x4 zero4 = {0, 0, 0, 0};
  i32x4 accA[4][4], accB[4][4];
  #pragma unroll
  for (int mf = 0; mf < 4; ++mf)
    #pragma unroll
    for (int nf = 0; nf < 4; ++nf){ accA[mf][nf] = zero4; accB[mf][nf] = zero4; }

  uint4 pa, pb[8];
  k2_load(z, wa, wb, m0, k0, tid, pa, pb);

  #pragma unroll 1
  for (int kc = 0; kc < KCH; kc += BK2){
    {
      int row = tid >> 2, c16 = tid & 3;
      *(uint4*)(Al + row * 80 + c16 * 16) = pa;
    }
    #pragma unroll
    for (int i = 0; i < 8; ++i){
      int idx = tid + 256 * i;
      int sel = idx >> 10;
      int r   = (idx >> 2) & 255;
      int c16 = idx & 3;
      *(uint4*)(Bw + (sel * 256 + r) * 80 + c16 * 16) = pb[i];
    }
    __syncthreads();

    if (kc + BK2 < KCH) k2_load(z, wa, wb, m0, k0 + kc + BK2, tid, pa, pb);

    i32x4 af[4], ba[4], bbf[4];
    #pragma unroll
    for (int mf = 0; mf < 4; ++mf)
      af[mf] = *(const i32x4*)(Al + (mf * 16 + lr) * 80 + lq * 16);
    #pragma unroll
    for (int nf = 0; nf < 4; ++nf){
      ba[nf]  = *(const i32x4*)(Bw + (w * 64 + nf * 16 + lr) * 80 + lq * 16);
      bbf[nf] = *(const i32x4*)(Bw + (256 + w * 64 + nf * 16 + lr) * 80 + lq * 16);
    }
    #pragma unroll
    for (int mf = 0; mf < 4; ++mf)
      #pragma unroll
      for (int nf = 0; nf < 4; ++nf){
        accA[mf][nf] = __builtin_amdgcn_mfma_i32_16x16x64_i8(af[mf], ba[nf],  accA[mf][nf], 0, 0, 0);
        accB[mf][nf] = __builtin_amdgcn_mfma_i32_16x16x64_i8(af[mf], bbf[nf], accB[mf][nf], 0, 0, 0);
      }
    __syncthreads();
  }

  #pragma unroll
  for (int mf = 0; mf < 4; ++mf)
    #pragma unroll
    for (int nf = 0; nf < 4; ++nf)
      #pragma unroll
      for (int r = 0; r < 4; ++r){
        int m = m0 + mf * 16 + lq * 4 + r;
        int n = w * 64 + nf * 16 + lr;
        if (m < M_ && n < N2_)
          P[((size_t)ks * M_ + m) * N2_ + n] =
            fmaf((float)accA[mf][nf][r], 0x1p-14f, (float)accB[mf][nf][r] * 0x1p-22f);
      }
}

// ---------------------------------------------------------------- K2b: reduce k-splits
__global__ __launch_bounds__(256) void k2b_reduce(const float* __restrict__ P,
                                                  float* __restrict__ G2){
  int j = blockIdx.x * 256 + threadIdx.x;
  if (j >= M_ * N2_) return;
  float s = 0.f;
  #pragma unroll
  for (int ks = 0; ks < KSPL; ++ks) s += P[(size_t)ks * (M_ * N2_) + j];
  G2[j] = s;
}

// ---------------------------------------------------------------- K3: LIF2+FC2+LIF3 scan
__global__ __launch_bounds__(256) void k3_scan(const float* __restrict__ G2,
                                               const float* __restrict__ w2,
                                               float* __restrict__ out){
  const int b = blockIdx.x;
  const int tid = threadIdx.x;
  const float w = (tid < N2_) ? w2[tid] : 0.f;
  float m2 = 0.f, m3 = 0.f;
  __shared__ float part[4];

  float nxt = (tid < N2_) ? G2[(size_t)b * N2_ + tid] : 0.f;
  for (int t = 0; t < T_; ++t){
    float g2v = nxt;
    if (t < T_ - 1 && tid < N2_) nxt = G2[(size_t)((t + 1) * B_ + b) * N2_ + tid];
    float nm = (m2 > 1.0f) ? 0.f : __fadd_rn(__fmul_rn(0.9f, m2), g2v);
    m2 = nm;
    float s = (m2 > 1.0f) ? w : 0.f;
    #pragma unroll
    for (int off = 32; off > 0; off >>= 1) s += __shfl_down(s, off, 64);
    if ((tid & 63) == 0) part[tid >> 6] = s;
    __syncthreads();
    if (tid == 0){
      float g3 = (part[0] + part[1]) + (part[2] + part[3]);
      m3 = __fadd_rn(__fmul_rn(0.95f, m3), g3);
      out[b * T_ + t] = m3;
    }
    __syncthreads();
  }
}

// ---------------------------------------------------------------- host
extern "C" void kernel_launch(void* const* d_in, const int* in_sizes, int n_in,
                              void* d_out, int out_size, void* d_ws, size_t ws_size,
                              hipStream_t stream){
  const float* x    = (const float*)d_in[0];
  const float* kern = (const float*)d_in[1];
  const float* w1   = (const float*)d_in[2];
  const float* w2   = (const float*)d_in[3];
  float* out = (float*)d_out;

  char* p = (char*)d_ws;
  unsigned char* z8 = (unsigned char*)p;     p += (size_t)M_ * K1N;
  char* wa = p;                              p += (size_t)NP_ * K1N;
  char* wb = p;                              p += (size_t)NP_ * K1N;
  float* P  = (float*)p;                     p += (size_t)KSPL * M_ * N2_ * 4;
  float* G2 = (float*)p;                     p += (size_t)M_ * N2_ * 4;

  size_t need = (size_t)(p - (char*)d_ws);
  if (ws_size < need) return;

  hipLaunchKernelGGL(k01_fused,  dim3(NCONV + NPERM), dim3(512), 0, stream,
                     x, kern, w1, z8, wa, wb);
  hipLaunchKernelGGL(k2_gemm,    dim3(MT2 * KSPL), dim3(256), 0, stream, z8, wa, wb, P);
  hipLaunchKernelGGL(k2b_reduce, dim3((M_ * N2_ + 255) / 256), dim3(256), 0, stream, P, G2);
  hipLaunchKernelGGL(k3_scan,    dim3(B_), dim3(256), 0, stream, G2, w2, out);
}